// Round 2
// baseline (283.252 us; speedup 1.0000x reference)
//
#include <hip/hip_runtime.h>
#include <hip/hip_cooperative_groups.h>

namespace cg = cooperative_groups;

// DTCWT level=3 on (8,512,512,3) f32 -> (8,1024,1024,3) f32.
// Single cooperative persistent kernel: three level-phases separated by
// grid.sync(). Per-level tile math identical to the verified 3-kernel
// version: Stage A row-filters (along H) with float4 global loads,
// register-transposes into an XOR-swizzled LDS tile; Stage B col-filters
// (along W) via b128 LDS reads, combines dual trees, 12 B/thread stores.
// afb: out[i] = sum_t f[t] * x[(2i+5-t) mod N]
// Tile(m,n) at rows [m*512,+512), cols [n*512,+512) of out; tile-local:
// lowpass 64x64 at (0,0); level-j bands (H=256,128,64): LH (0,H), HL (H,0), HH (H,H).

#define FF 0.08838834764832f
#define GG 0.01122679215254f
#define HHc 0.69587998903400f
#define AAc 0.03516384f
#define BBc 0.08832942f
#define CCc 0.23389032f
#define DDc 0.76027237f
#define EEc 0.58751830f
#define KKc 0.11430184f

// [bank: 0=Faf, 1=af][tree m][lo/hi][tap]
__device__ __constant__ float c_filt[2][2][2][10] = {
  { // Faf (first stage)
    { {0.f,-FF, FF, HHc, HHc, FF,-FF, GG, GG, 0.f},
      {0.f,-GG, GG, FF, FF,-HHc, HHc,-FF,-FF, 0.f} },
    { {GG, GG,-FF, FF, HHc, HHc, FF,-FF, 0.f, 0.f},
      {0.f, 0.f,-FF,-FF, HHc,-HHc, FF, FF, GG,-GG} }
  },
  { // af (q-shift, levels >= 1)
    { {AAc, 0.f,-BBc, CCc, DDc, EEc, 0.f,-KKc, 0.f, 0.f},
      {0.f, 0.f,-KKc, 0.f, EEc,-DDc, CCc, BBc, 0.f,-AAc} },
    { {0.f, 0.f,-KKc, 0.f, EEc, DDc, CCc,-BBc, 0.f, AAc},
      {-AAc, 0.f, BBc, CCc,-DDc, EEc, 0.f,-KKc, 0.f, 0.f} }
  }
};

__device__ __forceinline__ void cmb(float& a, float& b) {
  const float k = 0.70710678118654752440f;
  const float s = (a + b) * k, d = (a - b) * k;
  a = s; b = d;
}

// Injective bank swizzle on float4 indices: permutes low 3 bits (bank group)
// as a function of bits >=3. Range-preserving within 8-aligned octets.
__device__ __forceinline__ int swz4(int f4) { return f4 ^ ((f4 >> 3) & 7); }

// One tile of one level. Identical math to the verified per-level kernel;
// (jt, it, b) passed explicitly so a persistent block can iterate tiles.
template<int LVL, int N, int Ho, int Wo>
__device__ __forceinline__ void tile_level(
    const int jt, const int it, const int b,
    const float* __restrict__ src,
    float* __restrict__ llout,
    float* __restrict__ out,
    float* __restrict__ inter)
{
  constexpr int half = N / 2;
  constexpr int W2 = 2 * Wo + 8;               // col halo span
  constexpr int NF = (LVL == 0) ? 4 : 8;       // row-filter outputs per position
  constexpr int ROWF = 3 * N;                  // floats per image row
  constexpr int FL = 3 * W2;                   // flat floats per LDS row
  constexpr int SIF4 = (3 * W2 * NF) / 4 + 4;  // il-stride in float4 units
  constexpr size_t ZS = (size_t)8 * N * N * 3;
  constexpr size_t ZOUT = (size_t)8 * half * half * 3;

  const int i0 = it * Ho, j0 = jt * Wo;
  const int tid = threadIdx.x;

  int base = (2 * j0 - 4) * 3;                 // multiple of 4 floats (16B)
  if (base < 0) base += ROWF;

  // ---- Stage A: row filter along H, float4 global loads -> swizzled LDS ----
  constexpr int I4 = FL / 4;
  for (int item = tid; item < Ho * I4; item += 256) {
    const int il = item / I4;
    const int q4 = (item - il * I4) * 4;       // flat local (w*3+c), mult of 4
    int fg = base + q4;
    if (fg >= ROWF) fg -= ROWF;                // never straddles a float4
    const int ig = i0 + il;
    float acc[NF][4];
#pragma unroll
    for (int f = 0; f < NF; ++f)
#pragma unroll
      for (int k = 0; k < 4; ++k) acc[f][k] = 0.f;

    if constexpr (LVL == 0) {
      const float* sp = src + (size_t)b * N * ROWF + fg;
#pragma unroll
      for (int t = 0; t < 10; ++t) {
        const int r = (2 * ig + 5 - t) & (N - 1);
        const float4 v = *(const float4*)(sp + (size_t)r * ROWF);
#pragma unroll
        for (int f = 0; f < 4; ++f) {
          const float fc = c_filt[0][f >> 1][f & 1][t];
          acc[f][0] += fc * v.x; acc[f][1] += fc * v.y;
          acc[f][2] += fc * v.z; acc[f][3] += fc * v.w;
        }
      }
#pragma unroll
      for (int f = 0; f < 4; ++f)
#pragma unroll
        for (int k = 0; k < 4; ++k) acc[f][k] *= 0.5f;  // x/2 folded
    } else {
#pragma unroll
      for (int z = 0; z < 4; ++z) {
        const int m = z >> 1;
        const float* sp = src + (size_t)z * ZS + (size_t)b * N * ROWF + fg;
#pragma unroll
        for (int t = 0; t < 10; ++t) {
          const int r = (2 * ig + 5 - t) & (N - 1);
          const float4 v = *(const float4*)(sp + (size_t)r * ROWF);
          const float fl = c_filt[1][m][0][t], fh = c_filt[1][m][1][t];
          acc[2 * z][0] += fl * v.x; acc[2 * z][1] += fl * v.y;
          acc[2 * z][2] += fl * v.z; acc[2 * z][3] += fl * v.w;
          acc[2 * z + 1][0] += fh * v.x; acc[2 * z + 1][1] += fh * v.y;
          acc[2 * z + 1][2] += fh * v.z; acc[2 * z + 1][3] += fh * v.w;
        }
      }
    }
    // transpose-write: per flat position fq, NF filters contiguous as float4s.
    // NF=4: float4 index = fq. NF=8: float4 indices = 2*fq, 2*fq+1.
#pragma unroll
    for (int k = 0; k < 4; ++k) {
      const int fq = q4 + k;
      if constexpr (NF == 4) {
        float4 w = make_float4(acc[0][k], acc[1][k], acc[2][k], acc[3][k]);
        *(float4*)&inter[(il * SIF4 + swz4(fq)) * 4] = w;
      } else {
        float4 w0 = make_float4(acc[0][k], acc[1][k], acc[2][k], acc[3][k]);
        float4 w1 = make_float4(acc[4][k], acc[5][k], acc[6][k], acc[7][k]);
        *(float4*)&inter[(il * SIF4 + swz4(2 * fq)) * 4] = w0;
        *(float4*)&inter[(il * SIF4 + swz4(2 * fq + 1)) * 4] = w1;
      }
    }
  }
  __syncthreads();

  // ---- Stage B: col filter along W from LDS, combine, contiguous stores ----
  if (tid < Ho * Wo) {
    const int il = tid / Wo, jl = tid - (tid / Wo) * Wo;
    float LL[4][3] = {}, LH[4][3] = {}, HL[4][3] = {}, HH[4][3] = {};
#pragma unroll
    for (int s = 0; s < 10; ++s) {
      const int wl = 2 * jl + 9 - s;
#pragma unroll
      for (int c = 0; c < 3; ++c) {
        if constexpr (LVL == 0) {
          const int f4 = wl * 3 + c;
          const float4 v = *(const float4*)&inter[(il * SIF4 + swz4(f4)) * 4];
          const float a0 = v.x, d0 = v.y, a1 = v.z, d1 = v.w;
#pragma unroll
          for (int n = 0; n < 2; ++n) {
            const float fl = c_filt[0][n][0][s], fh = c_filt[0][n][1][s];
            LL[n][c] += fl * a0; LH[n][c] += fh * a0;
            HL[n][c] += fl * d0; HH[n][c] += fh * d0;
            LL[2 + n][c] += fl * a1; LH[2 + n][c] += fh * a1;
            HL[2 + n][c] += fl * d1; HH[2 + n][c] += fh * d1;
          }
        } else {
          const int f4 = (wl * 3 + c) * 2;
          const float4 v0 = *(const float4*)&inter[(il * SIF4 + swz4(f4)) * 4];
          const float4 v1 = *(const float4*)&inter[(il * SIF4 + swz4(f4 + 1)) * 4];
          const float az[4] = {v0.x, v0.z, v1.x, v1.z};
          const float dz[4] = {v0.y, v0.w, v1.y, v1.w};
#pragma unroll
          for (int z = 0; z < 4; ++z) {
            const int n = z & 1;
            const float fl = c_filt[1][n][0][s], fh = c_filt[1][n][1][s];
            LL[z][c] += fl * az[z]; LH[z][c] += fh * az[z];
            HL[z][c] += fl * dz[z]; HH[z][c] += fh * dz[z];
          }
        }
      }
    }
#pragma unroll
    for (int c = 0; c < 3; ++c) {
      cmb(LH[0][c], LH[3][c]); cmb(LH[1][c], LH[2][c]);
      cmb(HL[0][c], HL[3][c]); cmb(HL[1][c], HL[2][c]);
      cmb(HH[0][c], HH[3][c]); cmb(HH[1][c], HH[2][c]);
    }
    const int ig = i0 + il, jg = j0 + jl;
    const size_t outB = (size_t)b * (1024u * 1024u * 3u);
#pragma unroll
    for (int z = 0; z < 4; ++z) {
      const int m = z >> 1, n = z & 1;
      const int r0 = m * 512, c0 = n * 512;
      float* pLL;
      if constexpr (LVL == 2)
        pLL = out + outB + ((size_t)(r0 + ig) * 1024 + (c0 + jg)) * 3;
      else
        pLL = llout + (size_t)z * ZOUT + (((size_t)b * half + ig) * half + jg) * 3;
      pLL[0] = LL[z][0]; pLL[1] = LL[z][1]; pLL[2] = LL[z][2];
      float* pLH = out + outB + ((size_t)(r0 + ig) * 1024 + (c0 + half + jg)) * 3;
      pLH[0] = LH[z][0]; pLH[1] = LH[z][1]; pLH[2] = LH[z][2];
      float* pHL = out + outB + ((size_t)(r0 + half + ig) * 1024 + (c0 + jg)) * 3;
      pHL[0] = HL[z][0]; pHL[1] = HL[z][1]; pHL[2] = HL[z][2];
      float* pHH = out + outB + ((size_t)(r0 + half + ig) * 1024 + (c0 + half + jg)) * 3;
      pHH[0] = HH[z][0]; pHH[1] = HH[z][1]; pHH[2] = HH[z][2];
    }
  }
}

// LDS: max over levels of Ho*SIF4*4 floats.
//  L0: 8*220*4 = 7040;  L1/L2: 8*244*4 = 7808 floats = 31232 B.
#define INTER_FLOATS 7808

// ---- Single cooperative kernel: all 3 levels, grid-synced ----
__global__ __launch_bounds__(256, 2) void dtcwt_all(
    const float* __restrict__ x,
    float* __restrict__ LL1,
    float* __restrict__ LL2,
    float* __restrict__ out)
{
  __shared__ __align__(16) float inter[INTER_FLOATS];
  cg::grid_group grid = cg::this_grid();
  const int gb = blockIdx.x;
  const int G  = gridDim.x;

  // L0: 512->256. Tiles Ho=8 x Wo=32: 8(jt) x 32(it) x 8(b) = 2048 units.
  for (int t = gb; t < 2048; t += G) {
    tile_level<0, 512, 8, 32>(t & 7, (t >> 3) & 31, t >> 8, x, LL1, out, inter);
    __syncthreads();  // LDS reuse across tile iterations
  }
  grid.sync();
  // L1: 256->128. Tiles Ho=8 x Wo=16: 8(jt) x 16(it) x 8(b) = 1024 units.
  for (int t = gb; t < 1024; t += G) {
    tile_level<1, 256, 8, 16>(t & 7, (t >> 3) & 15, t >> 7, LL1, LL2, out, inter);
    __syncthreads();
  }
  grid.sync();
  // L2: 128->64. Tiles Ho=8 x Wo=16: 4(jt) x 8(it) x 8(b) = 256 units.
  for (int t = gb; t < 256; t += G) {
    tile_level<2, 128, 8, 16>(t & 3, (t >> 2) & 7, t >> 5, LL2, nullptr, out, inter);
    __syncthreads();
  }
}

// ---- Fallback: original 3-kernel path (used only if coop launch unavailable) ----
template<int LVL, int N, int Ho, int Wo>
__global__ __launch_bounds__(256) void fused_level(
    const float* __restrict__ src,
    float* __restrict__ llout,
    float* __restrict__ out)
{
  __shared__ __align__(16) float inter[INTER_FLOATS];
  tile_level<LVL, N, Ho, Wo>(blockIdx.x, blockIdx.y, blockIdx.z,
                             src, llout, out, inter);
}

extern "C" void kernel_launch(void* const* d_in, const int* in_sizes, int n_in,
                              void* d_out, int out_size, void* d_ws, size_t ws_size,
                              hipStream_t stream) {
  (void)in_sizes; (void)n_in; (void)out_size; (void)ws_size;
  const float* x = (const float*)d_in[0];
  float* out = (float*)d_out;
  float* LL1 = (float*)d_ws;        // 4*8*256*256*3 = 6,291,456 floats
  float* LL2 = LL1 + 6291456;       // 4*8*128*128*3 = 1,572,864 floats

  static int coop_grid = -2;        // -2 = uninitialized, -1 = unavailable
  if (coop_grid == -2) {
    int dev = 0;
    (void)hipGetDevice(&dev);
    int has_coop = 0;
    (void)hipDeviceGetAttribute(&has_coop, hipDeviceAttributeCooperativeLaunch, dev);
    int nb = 0;
    if (has_coop) {
      if (hipOccupancyMaxActiveBlocksPerMultiprocessor(&nb, dtcwt_all, 256, 0)
          != hipSuccess)
        nb = 0;
    }
    int ncu = 0;
    (void)hipDeviceGetAttribute(&ncu, hipDeviceAttributeMultiprocessorCount, dev);
    if (ncu <= 0) ncu = 256;
    coop_grid = (nb >= 1) ? nb * ncu : -1;
    if (coop_grid > 2048) coop_grid = 2048;
  }

  if (coop_grid > 0) {
    void* args[] = {(void*)&x, (void*)&LL1, (void*)&LL2, (void*)&out};
    hipError_t e = hipLaunchCooperativeKernel(dtcwt_all, dim3(coop_grid),
                                              dim3(256), args, 0u, stream);
    if (e == hipSuccess) return;
    coop_grid = -1;  // permanent fallback
  }

  // L0: 512->256. Tile 8x32.
  fused_level<0, 512, 8, 32><<<dim3(8, 32, 8), 256, 0, stream>>>(x, LL1, out);
  // L1: 256->128. Tile 8x16.
  fused_level<1, 256, 8, 16><<<dim3(8, 16, 8), 256, 0, stream>>>(LL1, LL2, out);
  // L2: 128->64. Tile 8x16.
  fused_level<2, 128, 8, 16><<<dim3(4, 8, 8), 256, 0, stream>>>(LL2, nullptr, out);
}